// Round 1
// baseline (2643.602 us; speedup 1.0000x reference)
//
#include <hip/hip_runtime.h>

#define NA 100000
#define MN 12
#define KE 41
#define N0C 2500
#define EPSBN 1e-5f

__device__ __forceinline__ float softplusf(float x){
  float e = __expf(-fabsf(x));
  return fmaxf(x, 0.f) + __logf(1.f + e);
}
__device__ __forceinline__ float sigmoidf(float x){
  return __fdividef(1.f, 1.f + __expf(-x));
}
__device__ __forceinline__ int waveid(){
  return __builtin_amdgcn_readfirstlane((int)((blockIdx.x * blockDim.x + threadIdx.x) >> 6));
}

// ---------------- embedding: h = atom_fea @ emb_W + emb_b  (N,92)@(92,64) ----------------
__global__ __launch_bounds__(256) void k_embed(const float* __restrict__ af,
                                               const float* __restrict__ W,
                                               const float* __restrict__ b,
                                               float* __restrict__ h, int nw)
{
  int t = threadIdx.x & 63;
  int wid = waveid();
  float bias = b[t];
  for (int n0 = wid * 2; n0 < NA; n0 += nw * 2) {
    int n1 = n0 + 1;
    bool has1 = (n1 < NA);
    const float* a0 = af + (size_t)n0 * 92;
    const float* a1 = af + (size_t)(has1 ? n1 : n0) * 92;
    float acc0 = bias, acc1 = bias;
#pragma unroll 4
    for (int k = 0; k < 92; ++k) {
      float w = W[k * 64 + t];          // 23.5 KB, L1-resident
      acc0 += a0[k] * w;                // a*: wave-uniform -> scalar loads
      acc1 += a1[k] * w;
    }
    h[(size_t)n0 * 64 + t] = acc0;
    if (has1) h[(size_t)n1 * 64 + t] = acc1;
  }
}

// ---------------- hW = h @ [W_self | W_nbr]  (N,64)@(64,256) ----------------
__global__ __launch_bounds__(256) void k_hw(const float* __restrict__ h,
                                            const float* __restrict__ fcW, // fc_W[l], (169,128)
                                            float* __restrict__ hW, int nw)
{
  __shared__ float Wl[64 * 256];        // Wl[c][j]: j<128 self (row c), j>=128 nbr (row 64+c)
  for (int i = threadIdx.x; i < 64 * 256; i += 256) {
    int c = i >> 8, j = i & 255;
    Wl[i] = fcW[(c + ((j >> 7) << 6)) * 128 + (j & 127)];
  }
  __syncthreads();
  int t = threadIdx.x & 63;
  int wid = waveid();
  const float4* W4 = (const float4*)Wl;
  for (int n0 = wid * 2; n0 < NA; n0 += nw * 2) {
    int n1 = n0 + 1;
    bool has1 = (n1 < NA);
    const float* ha = h + (size_t)n0 * 64;
    const float* hb = h + (size_t)(has1 ? n1 : n0) * 64;
    float4 A0 = {0,0,0,0}, A1 = {0,0,0,0};
#pragma unroll 4
    for (int c = 0; c < 64; ++c) {
      float4 w = W4[c * 64 + t];        // lane t owns output cols 4t..4t+3
      float x0 = ha[c], x1 = hb[c];     // wave-uniform -> scalar loads
      A0.x += x0 * w.x; A0.y += x0 * w.y; A0.z += x0 * w.z; A0.w += x0 * w.w;
      A1.x += x1 * w.x; A1.y += x1 * w.y; A1.z += x1 * w.z; A1.w += x1 * w.w;
    }
    ((float4*)(hW + (size_t)n0 * 256))[t] = A0;
    if (has1) ((float4*)(hW + (size_t)n1 * 256))[t] = A1;
  }
}

// ---------------- conv pass: stats (APPLY=0) / apply (APPLY=1) ----------------
// lane t owns g columns {t, t+64}. W_e column pair held in 82 VGPRs.
template<int APPLY>
__global__ __launch_bounds__(256) void k_conv(const float* __restrict__ hW,
                                              const float* __restrict__ e,
                                              const int* __restrict__ idx,
                                              const float* __restrict__ We,   // fc_W[l] rows 128..168
                                              const float* __restrict__ scsh, // [sc128|sh128]
                                              float* __restrict__ summed,
                                              float* __restrict__ stats,
                                              int nw)
{
  int t = threadIdx.x & 63;
  int wid = waveid();
  float we0[KE], we1[KE];
#pragma unroll
  for (int k = 0; k < KE; ++k) {
    we0[k] = We[k * 128 + t];
    we1[k] = We[k * 128 + 64 + t];
  }
  float sc0 = 0, sh0 = 0, sc1 = 0, sh1 = 0;
  if (APPLY) { sc0 = scsh[t]; sc1 = scsh[t + 64]; sh0 = scsh[128 + t]; sh1 = scsh[192 + t]; }
  float s0 = 0, q0 = 0, s1 = 0, q1 = 0;

  for (int n = wid; n < NA; n += nw) {
    const int* ip = idx + n * MN;
    int nbs[MN];
#pragma unroll
    for (int m = 0; m < MN; ++m) nbs[m] = ip[m];   // wave-uniform -> s_load
    float self0 = hW[(size_t)n * 256 + t];
    float self1 = hW[(size_t)n * 256 + 64 + t];
    const float* ep0 = e + (size_t)n * (MN * KE);
    float acc = 0.f;
#pragma unroll 2
    for (int m = 0; m < MN; ++m) {
      int nb = nbs[m];
      float nb0 = hW[(size_t)nb * 256 + 128 + t];
      float nb1 = hW[(size_t)nb * 256 + 192 + t];
      const float* ep = ep0 + m * KE;
      float a0 = 0, b0 = 0, a1 = 0, b1 = 0;
#pragma unroll
      for (int k = 0; k < KE - 1; k += 2) {
        float e0 = ep[k], e1 = ep[k + 1];           // wave-uniform -> s_load
        a0 += e0 * we0[k];     a1 += e0 * we1[k];
        b0 += e1 * we0[k + 1]; b1 += e1 * we1[k + 1];
      }
      float el = ep[KE - 1];
      a0 += el * we0[KE - 1]; a1 += el * we1[KE - 1];
      float g0 = self0 + nb0 + a0 + b0;
      float g1 = self1 + nb1 + a1 + b1;
      if (APPLY) {
        float f  = sigmoidf(g0 * sc0 + sh0);
        float cr = softplusf(g1 * sc1 + sh1);
        acc += f * cr;
      } else {
        s0 += g0; q0 += g0 * g0;
        s1 += g1; q1 += g1 * g1;
      }
    }
    if (APPLY) {
      summed[(size_t)n * 64 + t] = acc;
      s0 += acc; q0 += acc * acc;                    // BN2 stats
    }
  }
  if (APPLY) {
    atomicAdd(&stats[t], s0);
    atomicAdd(&stats[64 + t], q0);
  } else {
    atomicAdd(&stats[t], s0);          // sum col t
    atomicAdd(&stats[64 + t], s1);     // sum col t+64
    atomicAdd(&stats[128 + t], q0);    // sumsq col t
    atomicAdd(&stats[192 + t], q1);    // sumsq col t+64
  }
}

// ---------------- BN finalize: scale/shift from sums ----------------
__global__ void k_fin1(const float* __restrict__ st, const float* __restrict__ g,
                       const float* __restrict__ b, float* __restrict__ scsh)
{
  int j = threadIdx.x;                 // 128
  float inv = 1.f / (float)(NA * MN);
  float mean = st[j] * inv;
  float var  = st[128 + j] * inv - mean * mean;
  float rstd = rsqrtf(var + EPSBN);
  float sc = g[j] * rstd;
  scsh[j] = sc;
  scsh[128 + j] = b[j] - mean * sc;
}
__global__ void k_fin2(const float* __restrict__ st, const float* __restrict__ g,
                       const float* __restrict__ b, float* __restrict__ scsh)
{
  int j = threadIdx.x;                 // 64
  float inv = 1.f / (float)NA;
  float mean = st[j] * inv;
  float var  = st[64 + j] * inv - mean * mean;
  float rstd = rsqrtf(var + EPSBN);
  float sc = g[j] * rstd;
  scsh[j] = sc;
  scsh[64 + j] = b[j] - mean * sc;
}

// ---------------- h = softplus(h + BN2(summed)) ----------------
__global__ __launch_bounds__(256) void k_bn2res(float* __restrict__ h,
                                                const float* __restrict__ summed,
                                                const float* __restrict__ scsh) // [sc64|sh64]
{
  int tot = NA * 64 / 4;
  const float4* s4 = (const float4*)summed;
  float4* h4 = (float4*)h;
  for (int i = blockIdx.x * blockDim.x + threadIdx.x; i < tot; i += gridDim.x * blockDim.x) {
    int c4 = i & 15;
    float4 sc = ((const float4*)scsh)[c4];
    float4 sh = ((const float4*)(scsh + 64))[c4];
    float4 hv = h4[i], sv = s4[i];
    hv.x = softplusf(hv.x + sv.x * sc.x + sh.x);
    hv.y = softplusf(hv.y + sv.y * sc.y + sh.y);
    hv.z = softplusf(hv.z + sv.z * sc.z + sh.z);
    hv.w = softplusf(hv.w + sv.w * sc.w + sh.w);
    h4[i] = hv;
  }
}

// ---------------- segment-sum pool (crystal_atom_idx is sorted) ----------------
__global__ __launch_bounds__(256) void k_pool(const float* __restrict__ h,
                                              const int* __restrict__ cidx,
                                              float* __restrict__ csum,
                                              float* __restrict__ ccnt, int nw)
{
  int t = threadIdx.x & 63;
  int wid = waveid();
  int chunk = (NA + nw - 1) / nw;
  int n0 = wid * chunk;
  int n1 = min(n0 + chunk, NA);
  if (n0 >= NA) return;
  float acc = 0.f, cacc = 0.f;
  int cur = -1;
  for (int n = n0; n < n1; ++n) {
    int ci = cidx[n];                  // wave-uniform
    if (ci != cur) {
      if (cur >= 0) {
        atomicAdd(&csum[(size_t)cur * 64 + t], acc);
        if (t == 0) atomicAdd(&ccnt[cur], cacc);
      }
      cur = ci; acc = 0.f; cacc = 0.f;
    }
    acc += h[(size_t)n * 64 + t];
    cacc += 1.f;
  }
  if (cur >= 0) {
    atomicAdd(&csum[(size_t)cur * 64 + t], acc);
    if (t == 0) atomicAdd(&ccnt[cur], cacc);
  }
}

// ---------------- head: out = softplus(softplus(crys)@Wh + bh) @ Wo + bo ----------------
__global__ __launch_bounds__(256) void k_head(const float* __restrict__ csum,
                                              const float* __restrict__ ccnt,
                                              const float* __restrict__ Wh,   // (64,128)
                                              const float* __restrict__ bh,
                                              const float* __restrict__ Wo,   // (128,1)
                                              const float* __restrict__ bo,
                                              float* __restrict__ out)
{
  __shared__ float Wl[64 * 128];
  for (int i = threadIdx.x; i < 64 * 128; i += 256) Wl[i] = Wh[i];
  __syncthreads();
  int t = threadIdx.x & 63;
  int ci = blockIdx.x * 4 + (threadIdx.x >> 6);
  if (ci >= N0C) return;
  float cnt = fmaxf(ccnt[ci], 1.f);
  float x = softplusf(csum[(size_t)ci * 64 + t] / cnt);
  float acc0 = 0.f, acc1 = 0.f;
#pragma unroll 4
  for (int c = 0; c < 64; ++c) {
    float xc = __shfl(x, c, 64);
    acc0 += xc * Wl[c * 128 + t];
    acc1 += xc * Wl[c * 128 + 64 + t];
  }
  float z0 = softplusf(acc0 + bh[t]);
  float z1 = softplusf(acc1 + bh[64 + t]);
  float part = z0 * Wo[t] + z1 * Wo[64 + t];
#pragma unroll
  for (int s = 32; s >= 1; s >>= 1) part += __shfl_xor(part, s, 64);
  if (t == 0) out[ci] = part + bo[0];
}

extern "C" void kernel_launch(void* const* d_in, const int* in_sizes, int n_in,
                              void* d_out, int out_size, void* d_ws, size_t ws_size,
                              hipStream_t stream)
{
  const float* af    = (const float*)d_in[0];
  const float* nbr   = (const float*)d_in[1];
  const int*   nidx  = (const int*)d_in[2];
  const int*   cidx  = (const int*)d_in[3];
  const float* embW  = (const float*)d_in[4];
  const float* embB  = (const float*)d_in[5];
  const float* fcW   = (const float*)d_in[6];
  // d_in[7] = fc_b: cancelled by BatchNorm (mean subtraction) -> unused
  const float* bn1g  = (const float*)d_in[8];
  const float* bn1b  = (const float*)d_in[9];
  const float* bn2g  = (const float*)d_in[10];
  const float* bn2b  = (const float*)d_in[11];
  const float* headW = (const float*)d_in[12];
  const float* headB = (const float*)d_in[13];
  const float* outW  = (const float*)d_in[14];
  const float* outB  = (const float*)d_in[15];
  float* out = (float*)d_out;

  float* ws = (float*)d_ws;
  size_t off = 0;
  float* h      = ws + off; off += (size_t)NA * 64;
  float* hW     = ws + off; off += (size_t)NA * 256;
  float* summed = ws + off; off += (size_t)NA * 64;
  float* zr     = ws + off;                 // zeroed region start
  float* stats1 = zr;                       // 3*256
  float* stats2 = stats1 + 3 * 256;         // 3*128
  float* csum   = stats2 + 3 * 128;         // 2500*64
  float* ccnt   = csum + (size_t)N0C * 64;  // 2500
  size_t zcount = 3 * 256 + 3 * 128 + (size_t)N0C * 64 + N0C;
  float* scsh1  = ccnt + N0C;               // 3*256 (written before read)
  float* scsh2  = scsh1 + 3 * 256;          // 3*128

  hipMemsetAsync(zr, 0, zcount * sizeof(float), stream);

  k_embed<<<512, 256, 0, stream>>>(af, embW, embB, h, 2048);

  for (int l = 0; l < 3; ++l) {
    const float* Wl = fcW + (size_t)l * 169 * 128;
    const float* We = Wl + 128 * 128;
    k_hw<<<512, 256, 0, stream>>>(h, Wl, hW, 2048);
    k_conv<0><<<2048, 256, 0, stream>>>(hW, nbr, nidx, We, nullptr, nullptr,
                                        stats1 + l * 256, 8192);
    k_fin1<<<1, 128, 0, stream>>>(stats1 + l * 256, bn1g + l * 128, bn1b + l * 128,
                                  scsh1 + l * 256);
    k_conv<1><<<2048, 256, 0, stream>>>(hW, nbr, nidx, We, scsh1 + l * 256, summed,
                                        stats2 + l * 128, 8192);
    k_fin2<<<1, 64, 0, stream>>>(stats2 + l * 128, bn2g + l * 64, bn2b + l * 64,
                                 scsh2 + l * 128);
    k_bn2res<<<2048, 256, 0, stream>>>(h, summed, scsh2 + l * 128);
  }

  k_pool<<<512, 256, 0, stream>>>(h, cidx, csum, ccnt, 2048);
  k_head<<<625, 256, 0, stream>>>(csum, ccnt, headW, headB, outW, outB, out);
}

// Round 2
// 2220.579 us; speedup vs baseline: 1.1905x; 1.1905x over previous
//
#include <hip/hip_runtime.h>

#define NA 100000
#define MN 12
#define KE 41
#define N0C 2500
#define EPSBN 1e-5f

typedef _Float16 h2 __attribute__((ext_vector_type(2)));
typedef unsigned int uint;
union H2U { uint u; h2 h; };

#if __has_builtin(__builtin_amdgcn_fdot2)
#define FDOT2(a, b, c) __builtin_amdgcn_fdot2((a), (b), (c), false)
#else
__device__ __forceinline__ float fdot2_sw(h2 a, h2 b, float c) {
  return c + (float)a[0] * (float)b[0] + (float)a[1] * (float)b[1];
}
#define FDOT2(a, b, c) fdot2_sw((a), (b), (c))
#endif

__device__ __forceinline__ float softplusf(float x){
  float e = __expf(-fabsf(x));
  return fmaxf(x, 0.f) + __logf(1.f + e);
}
__device__ __forceinline__ float sigmoidf(float x){
  return __fdividef(1.f, 1.f + __expf(-x));
}
__device__ __forceinline__ int waveid(){
  return __builtin_amdgcn_readfirstlane((int)((blockIdx.x * blockDim.x + threadIdx.x) >> 6));
}

// ---------------- e (N,M,41) f32 -> ef (N,M,21 dwords of half2, last half zero-pad) ----------
__global__ __launch_bounds__(256) void k_cast_e(const float* __restrict__ e,
                                                uint* __restrict__ ef)
{
  const int TOT = NA * MN * 21;
  for (int i = blockIdx.x * 256 + threadIdx.x; i < TOT; i += gridDim.x * 256) {
    int r = i / 21, k2 = i - r * 21;
    const float* row = e + (size_t)r * KE;
    float a = row[2 * k2];
    float b = (k2 < 20) ? row[2 * k2 + 1] : 0.f;
    H2U cv; cv.h = h2{(_Float16)a, (_Float16)b};
    ef[i] = cv.u;
  }
}

// ---------------- embedding: h = atom_fea @ emb_W + emb_b  (N,92)@(92,64) ----------------
__global__ __launch_bounds__(256) void k_embed(const float* __restrict__ af,
                                               const float* __restrict__ W,
                                               const float* __restrict__ b,
                                               float* __restrict__ h, int nw)
{
  int t = threadIdx.x & 63;
  int wid = waveid();
  float bias = b[t];
  for (int n0 = wid * 2; n0 < NA; n0 += nw * 2) {
    int n1 = n0 + 1;
    bool has1 = (n1 < NA);
    const float* a0 = af + (size_t)n0 * 92;
    const float* a1 = af + (size_t)(has1 ? n1 : n0) * 92;
    float acc0 = bias, acc1 = bias;
#pragma unroll 4
    for (int k = 0; k < 92; ++k) {
      float w = W[k * 64 + t];
      acc0 += a0[k] * w;
      acc1 += a1[k] * w;
    }
    h[(size_t)n0 * 64 + t] = acc0;
    if (has1) h[(size_t)n1 * 64 + t] = acc1;
  }
}

// ---------------- hWc = pack_f16( h @ [W_self | W_nbr] )  (N,64) x uint2 ----------------
// hWc[n][t] = { half2(self col t, self col 64+t), half2(nbr col t, nbr col 64+t) }
__global__ __launch_bounds__(256) void k_hw(const float* __restrict__ h,
                                            const float* __restrict__ fcW, // (169,128)
                                            uint2* __restrict__ hWc, int nw)
{
  __shared__ float Wl[64 * 256];   // float4 per (c,t): {Ws[c][t],Ws[c][64+t],Wn[c][t],Wn[c][64+t]}
  for (int i = threadIdx.x; i < 64 * 256; i += 256) {
    int c = i >> 8, q = i & 255;
    int j = q & 63, part = q >> 6;
    Wl[(c * 64 + j) * 4 + part] = fcW[(c + ((part >> 1) << 6)) * 128 + ((part & 1) << 6) + j];
  }
  __syncthreads();
  int t = threadIdx.x & 63;
  int wid = waveid();
  const float4* W4 = (const float4*)Wl;
  for (int n0 = wid * 2; n0 < NA; n0 += nw * 2) {
    int n1 = n0 + 1;
    bool has1 = (n1 < NA);
    const float* ha = h + (size_t)n0 * 64;
    const float* hb = h + (size_t)(has1 ? n1 : n0) * 64;
    float4 A = {0,0,0,0}, B = {0,0,0,0};
#pragma unroll 4
    for (int c = 0; c < 64; ++c) {
      float4 w = W4[c * 64 + t];
      float x0 = ha[c], x1 = hb[c];
      A.x += x0 * w.x; A.y += x0 * w.y; A.z += x0 * w.z; A.w += x0 * w.w;
      B.x += x1 * w.x; B.y += x1 * w.y; B.z += x1 * w.z; B.w += x1 * w.w;
    }
    H2U p0, p1;
    p0.h = h2{(_Float16)A.x, (_Float16)A.y};
    p1.h = h2{(_Float16)A.z, (_Float16)A.w};
    hWc[(size_t)n0 * 64 + t] = uint2{p0.u, p1.u};
    if (has1) {
      p0.h = h2{(_Float16)B.x, (_Float16)B.y};
      p1.h = h2{(_Float16)B.z, (_Float16)B.w};
      hWc[(size_t)n1 * 64 + t] = uint2{p0.u, p1.u};
    }
  }
}

// ---------------- conv pass: stats (APPLY=0) / apply (APPLY=1) ----------------
// lane t owns g columns {t, t+64}; dot via v_dot2_f32_f16; gathers prefetched per atom.
template<int APPLY>
__global__ __launch_bounds__(256) void k_conv(const uint2* __restrict__ hWc,
                                              const uint* __restrict__ ef,
                                              const int* __restrict__ idx,
                                              const float* __restrict__ We,   // rows 128..168
                                              const float* __restrict__ scsh, // [sc128|sh128]
                                              float* __restrict__ summed,
                                              float* __restrict__ stats,
                                              int nw)
{
  int t = threadIdx.x & 63;
  int wid = waveid();
  h2 we0[21], we1[21];
#pragma unroll
  for (int k2 = 0; k2 < 21; ++k2) {
    float a0 = We[(2 * k2) * 128 + t];
    float b0 = (k2 < 20) ? We[(2 * k2 + 1) * 128 + t] : 0.f;
    float a1 = We[(2 * k2) * 128 + 64 + t];
    float b1 = (k2 < 20) ? We[(2 * k2 + 1) * 128 + 64 + t] : 0.f;
    we0[k2] = h2{(_Float16)a0, (_Float16)b0};
    we1[k2] = h2{(_Float16)a1, (_Float16)b1};
  }
  float sc0 = 0, sh0 = 0, sc1 = 0, sh1 = 0;
  if (APPLY) { sc0 = scsh[t]; sc1 = scsh[t + 64]; sh0 = scsh[128 + t]; sh1 = scsh[192 + t]; }
  float s0 = 0, q0 = 0, s1 = 0, q1 = 0;
  const uint* hWu = (const uint*)hWc;

  for (int n = wid; n < NA; n += nw) {
    const int* ip = idx + n * MN;
    int nbs[MN];
#pragma unroll
    for (int m = 0; m < MN; ++m) nbs[m] = ip[m];          // wave-uniform -> s_load
    uint nbp[MN];
#pragma unroll
    for (int m = 0; m < MN; ++m)                           // all gathers in flight first
      nbp[m] = hWu[(size_t)nbs[m] * 128 + 2 * t + 1];
    H2U sp; sp.u = hWu[(size_t)n * 128 + 2 * t];
    float self0 = (float)sp.h[0], self1 = (float)sp.h[1];
    const uint* ep = ef + (size_t)n * (MN * 21);
    float acc = 0.f;
#pragma unroll
    for (int m = 0; m < MN; ++m) {
      float d0a = 0.f, d0b = 0.f, d1a = 0.f, d1b = 0.f;    // 4 chains for ILP
#pragma unroll
      for (int k2 = 0; k2 < 20; k2 += 2) {
        H2U e0; e0.u = ep[m * 21 + k2];
        H2U e1; e1.u = ep[m * 21 + k2 + 1];
        d0a = FDOT2(e0.h, we0[k2], d0a);
        d1a = FDOT2(e0.h, we1[k2], d1a);
        d0b = FDOT2(e1.h, we0[k2 + 1], d0b);
        d1b = FDOT2(e1.h, we1[k2 + 1], d1b);
      }
      { H2U el; el.u = ep[m * 21 + 20];
        d0a = FDOT2(el.h, we0[20], d0a);
        d1a = FDOT2(el.h, we1[20], d1a); }
      H2U nv; nv.u = nbp[m];
      float g0 = self0 + (float)nv.h[0] + d0a + d0b;
      float g1 = self1 + (float)nv.h[1] + d1a + d1b;
      if (APPLY) {
        float f  = sigmoidf(g0 * sc0 + sh0);
        float cr = softplusf(g1 * sc1 + sh1);
        acc += f * cr;
      } else {
        s0 += g0; q0 += g0 * g0;
        s1 += g1; q1 += g1 * g1;
      }
    }
    if (APPLY) {
      summed[(size_t)n * 64 + t] = acc;
      s0 += acc; q0 += acc * acc;                          // BN2 stats
    }
  }
  if (APPLY) {
    atomicAdd(&stats[t], s0);
    atomicAdd(&stats[64 + t], q0);
  } else {
    atomicAdd(&stats[t], s0);
    atomicAdd(&stats[64 + t], s1);
    atomicAdd(&stats[128 + t], q0);
    atomicAdd(&stats[192 + t], q1);
  }
}

// ---------------- BN finalize ----------------
__global__ void k_fin1(const float* __restrict__ st, const float* __restrict__ g,
                       const float* __restrict__ b, float* __restrict__ scsh)
{
  int j = threadIdx.x;                 // 128
  float inv = 1.f / (float)(NA * MN);
  float mean = st[j] * inv;
  float var  = st[128 + j] * inv - mean * mean;
  float rstd = rsqrtf(var + EPSBN);
  float sc = g[j] * rstd;
  scsh[j] = sc;
  scsh[128 + j] = b[j] - mean * sc;
}
__global__ void k_fin2(const float* __restrict__ st, const float* __restrict__ g,
                       const float* __restrict__ b, float* __restrict__ scsh)
{
  int j = threadIdx.x;                 // 64
  float inv = 1.f / (float)NA;
  float mean = st[j] * inv;
  float var  = st[64 + j] * inv - mean * mean;
  float rstd = rsqrtf(var + EPSBN);
  float sc = g[j] * rstd;
  scsh[j] = sc;
  scsh[64 + j] = b[j] - mean * sc;
}

// ---------------- h = softplus(h + BN2(summed)) ----------------
__global__ __launch_bounds__(256) void k_bn2res(float* __restrict__ h,
                                                const float* __restrict__ summed,
                                                const float* __restrict__ scsh)
{
  int tot = NA * 64 / 4;
  const float4* s4 = (const float4*)summed;
  float4* h4 = (float4*)h;
  for (int i = blockIdx.x * blockDim.x + threadIdx.x; i < tot; i += gridDim.x * blockDim.x) {
    int c4 = i & 15;
    float4 sc = ((const float4*)scsh)[c4];
    float4 sh = ((const float4*)(scsh + 64))[c4];
    float4 hv = h4[i], sv = s4[i];
    hv.x = softplusf(hv.x + sv.x * sc.x + sh.x);
    hv.y = softplusf(hv.y + sv.y * sc.y + sh.y);
    hv.z = softplusf(hv.z + sv.z * sc.z + sh.z);
    hv.w = softplusf(hv.w + sv.w * sc.w + sh.w);
    h4[i] = hv;
  }
}

// ---------------- segment-sum pool (crystal_atom_idx is sorted) ----------------
__global__ __launch_bounds__(256) void k_pool(const float* __restrict__ h,
                                              const int* __restrict__ cidx,
                                              float* __restrict__ csum,
                                              float* __restrict__ ccnt, int nw)
{
  int t = threadIdx.x & 63;
  int wid = waveid();
  int chunk = (NA + nw - 1) / nw;
  int n0 = wid * chunk;
  int n1 = min(n0 + chunk, NA);
  if (n0 >= NA) return;
  float acc = 0.f, cacc = 0.f;
  int cur = -1;
  for (int n = n0; n < n1; ++n) {
    int ci = cidx[n];
    if (ci != cur) {
      if (cur >= 0) {
        atomicAdd(&csum[(size_t)cur * 64 + t], acc);
        if (t == 0) atomicAdd(&ccnt[cur], cacc);
      }
      cur = ci; acc = 0.f; cacc = 0.f;
    }
    acc += h[(size_t)n * 64 + t];
    cacc += 1.f;
  }
  if (cur >= 0) {
    atomicAdd(&csum[(size_t)cur * 64 + t], acc);
    if (t == 0) atomicAdd(&ccnt[cur], cacc);
  }
}

// ---------------- head ----------------
__global__ __launch_bounds__(256) void k_head(const float* __restrict__ csum,
                                              const float* __restrict__ ccnt,
                                              const float* __restrict__ Wh,   // (64,128)
                                              const float* __restrict__ bh,
                                              const float* __restrict__ Wo,   // (128,1)
                                              const float* __restrict__ bo,
                                              float* __restrict__ out)
{
  __shared__ float Wl[64 * 128];
  for (int i = threadIdx.x; i < 64 * 128; i += 256) Wl[i] = Wh[i];
  __syncthreads();
  int t = threadIdx.x & 63;
  int ci = blockIdx.x * 4 + (threadIdx.x >> 6);
  if (ci >= N0C) return;
  float cnt = fmaxf(ccnt[ci], 1.f);
  float x = softplusf(csum[(size_t)ci * 64 + t] / cnt);
  float acc0 = 0.f, acc1 = 0.f;
#pragma unroll 4
  for (int c = 0; c < 64; ++c) {
    float xc = __shfl(x, c, 64);
    acc0 += xc * Wl[c * 128 + t];
    acc1 += xc * Wl[c * 128 + 64 + t];
  }
  float z0 = softplusf(acc0 + bh[t]);
  float z1 = softplusf(acc1 + bh[64 + t]);
  float part = z0 * Wo[t] + z1 * Wo[64 + t];
#pragma unroll
  for (int s = 32; s >= 1; s >>= 1) part += __shfl_xor(part, s, 64);
  if (t == 0) out[ci] = part + bo[0];
}

extern "C" void kernel_launch(void* const* d_in, const int* in_sizes, int n_in,
                              void* d_out, int out_size, void* d_ws, size_t ws_size,
                              hipStream_t stream)
{
  const float* af    = (const float*)d_in[0];
  const float* nbr   = (const float*)d_in[1];
  const int*   nidx  = (const int*)d_in[2];
  const int*   cidx  = (const int*)d_in[3];
  const float* embW  = (const float*)d_in[4];
  const float* embB  = (const float*)d_in[5];
  const float* fcW   = (const float*)d_in[6];
  // d_in[7] = fc_b: cancelled by BatchNorm mean subtraction
  const float* bn1g  = (const float*)d_in[8];
  const float* bn1b  = (const float*)d_in[9];
  const float* bn2g  = (const float*)d_in[10];
  const float* bn2b  = (const float*)d_in[11];
  const float* headW = (const float*)d_in[12];
  const float* headB = (const float*)d_in[13];
  const float* outW  = (const float*)d_in[14];
  const float* outB  = (const float*)d_in[15];
  float* out = (float*)d_out;

  float* ws = (float*)d_ws;
  size_t off = 0;
  float* h      = ws + off; off += (size_t)NA * 64;        // 6.4M
  uint2* hWc    = (uint2*)(ws + off); off += (size_t)NA * 128;  // 12.8M dwords
  uint*  ef     = (uint*)(ws + off);  off += (size_t)NA * MN * 21; // 25.2M dwords
  float* summed = ws + off; off += (size_t)NA * 64;        // 6.4M
  float* zr     = ws + off;
  float* stats1 = zr;                       // 3*256
  float* stats2 = stats1 + 3 * 256;         // 3*128
  float* csum   = stats2 + 3 * 128;         // 2500*64
  float* ccnt   = csum + (size_t)N0C * 64;  // 2500
  size_t zcount = 3 * 256 + 3 * 128 + (size_t)N0C * 64 + N0C;
  float* scsh1  = ccnt + N0C;               // 3*256
  float* scsh2  = scsh1 + 3 * 256;          // 3*128

  hipMemsetAsync(zr, 0, zcount * sizeof(float), stream);

  k_cast_e<<<4096, 256, 0, stream>>>(nbr, ef);
  k_embed<<<512, 256, 0, stream>>>(af, embW, embB, h, 2048);

  for (int l = 0; l < 3; ++l) {
    const float* Wl = fcW + (size_t)l * 169 * 128;
    const float* We = Wl + 128 * 128;
    k_hw<<<512, 256, 0, stream>>>(h, Wl, hWc, 2048);
    k_conv<0><<<2048, 256, 0, stream>>>(hWc, ef, nidx, We, nullptr, nullptr,
                                        stats1 + l * 256, 8192);
    k_fin1<<<1, 128, 0, stream>>>(stats1 + l * 256, bn1g + l * 128, bn1b + l * 128,
                                  scsh1 + l * 256);
    k_conv<1><<<2048, 256, 0, stream>>>(hWc, ef, nidx, We, scsh1 + l * 256, summed,
                                        stats2 + l * 128, 8192);
    k_fin2<<<1, 64, 0, stream>>>(stats2 + l * 128, bn2g + l * 64, bn2b + l * 64,
                                 scsh2 + l * 128);
    k_bn2res<<<2048, 256, 0, stream>>>(h, summed, scsh2 + l * 128);
  }

  k_pool<<<512, 256, 0, stream>>>(h, cidx, csum, ccnt, 2048);
  k_head<<<625, 256, 0, stream>>>(csum, ccnt, headW, headB, outW, outB, out);
}

// Round 3
// 1624.459 us; speedup vs baseline: 1.6274x; 1.3670x over previous
//
#include <hip/hip_runtime.h>

#define NA 100000
#define MN 12
#define KE 41
#define N0C 2500
#define EPSBN 1e-5f
#define ROWDW 24                 // EF dwords per (n,m) row: 48 f16 (k 41..47 zero)
#define CONV_BLOCKS 1024
#define CONV_WAVES (CONV_BLOCKS * 4)

typedef _Float16 h2v __attribute__((ext_vector_type(2)));
typedef _Float16 h8v __attribute__((ext_vector_type(8)));
typedef float f4v __attribute__((ext_vector_type(4)));
typedef unsigned int uint;
union H2U { uint u; h2v h; };

__device__ __forceinline__ float softplusf(float x){
  float e = __expf(-fabsf(x));
  return fmaxf(x, 0.f) + __logf(1.f + e);
}
__device__ __forceinline__ float sigmoidf(float x){
  return __fdividef(1.f, 1.f + __expf(-x));
}
__device__ __forceinline__ int waveid(){
  return __builtin_amdgcn_readfirstlane((int)((blockIdx.x * blockDim.x + threadIdx.x) >> 6));
}

// ---- e (N,M,41) f32 -> EF [n][m][24 dwords of half2], k 41..47 zero ----
__global__ __launch_bounds__(256) void k_cast_e(const float* __restrict__ e,
                                                uint* __restrict__ EF)
{
  const int TOT = NA * MN * ROWDW;
  for (int i = blockIdx.x * 256 + threadIdx.x; i < TOT; i += gridDim.x * 256) {
    int r = i / ROWDW, k2 = i - r * ROWDW;
    const float* row = e + (size_t)r * KE;
    float a = 0.f, b = 0.f;
    if (k2 < 20) { a = row[2 * k2]; b = row[2 * k2 + 1]; }
    else if (k2 == 20) { a = row[40]; }
    H2U cv; cv.h = h2v{(_Float16)a, (_Float16)b};
    EF[i] = cv.u;
  }
}

// ---- embedding: h = atom_fea @ emb_W + emb_b ----
__global__ __launch_bounds__(256) void k_embed(const float* __restrict__ af,
                                               const float* __restrict__ W,
                                               const float* __restrict__ b,
                                               float* __restrict__ h, int nw)
{
  int t = threadIdx.x & 63;
  int wid = waveid();
  float bias = b[t];
  for (int n0 = wid * 2; n0 < NA; n0 += nw * 2) {
    int n1 = n0 + 1;
    bool has1 = (n1 < NA);
    const float* a0 = af + (size_t)n0 * 92;
    const float* a1 = af + (size_t)(has1 ? n1 : n0) * 92;
    float acc0 = bias, acc1 = bias;
#pragma unroll 4
    for (int k = 0; k < 92; ++k) {
      float w = W[k * 64 + t];
      acc0 += a0[k] * w;
      acc1 += a1[k] * w;
    }
    h[(size_t)n0 * 64 + t] = acc0;
    if (has1) h[(size_t)n1 * 64 + t] = acc1;
  }
}

// ---- hWs/hWn = pack_f16( h @ [W_self | W_nbr] ): pair = (col t, col t+64) ----
__global__ __launch_bounds__(256) void k_hw(const float* __restrict__ h,
                                            const float* __restrict__ fcW, // (169,128)
                                            uint* __restrict__ hWs,
                                            uint* __restrict__ hWn, int nw)
{
  __shared__ float Wl[64 * 256]; // float4 per (c,t): {Ws[c][t],Ws[c][64+t],Wn[c][t],Wn[c][64+t]}
  for (int i = threadIdx.x; i < 64 * 256; i += 256) {
    int c = i >> 8, q = i & 255;
    int j = q & 63, part = q >> 6;
    Wl[(c * 64 + j) * 4 + part] = fcW[(c + ((part >> 1) << 6)) * 128 + ((part & 1) << 6) + j];
  }
  __syncthreads();
  int t = threadIdx.x & 63;
  int wid = waveid();
  const float4* W4 = (const float4*)Wl;
  for (int n0 = wid * 2; n0 < NA; n0 += nw * 2) {
    int n1 = n0 + 1;
    bool has1 = (n1 < NA);
    const float* ha = h + (size_t)n0 * 64;
    const float* hb = h + (size_t)(has1 ? n1 : n0) * 64;
    float4 A = {0,0,0,0}, B = {0,0,0,0};
#pragma unroll 4
    for (int c = 0; c < 64; ++c) {
      float4 w = W4[c * 64 + t];
      float x0 = ha[c], x1 = hb[c];
      A.x += x0 * w.x; A.y += x0 * w.y; A.z += x0 * w.z; A.w += x0 * w.w;
      B.x += x1 * w.x; B.y += x1 * w.y; B.z += x1 * w.z; B.w += x1 * w.w;
    }
    H2U p0, p1;
    p0.h = h2v{(_Float16)A.x, (_Float16)A.y};
    p1.h = h2v{(_Float16)A.z, (_Float16)A.w};
    hWs[(size_t)n0 * 64 + t] = p0.u;
    hWn[(size_t)n0 * 64 + t] = p1.u;
    if (has1) {
      p0.h = h2v{(_Float16)B.x, (_Float16)B.y};
      p1.h = h2v{(_Float16)B.z, (_Float16)B.w};
      hWs[(size_t)n1 * 64 + t] = p0.u;
      hWn[(size_t)n1 * 64 + t] = p1.u;
    }
  }
}

// ---- conv pass: one wave per atom; g tile (16 x 128) via MFMA; LDS transpose; fused epilogue ----
template<int APPLY>
__global__ __launch_bounds__(256) void k_conv(const uint* __restrict__ EF,
                                              const uint* __restrict__ hWs,
                                              const uint* __restrict__ hWn,
                                              const int*  __restrict__ idx,
                                              const float* __restrict__ We,   // fcW rows 128..168
                                              const float* __restrict__ scsh, // [sc128|sh128]
                                              float* __restrict__ summed,
                                              float* __restrict__ stats)
{
  __shared__ float gt_all[4][16 * 132];
  int l = threadIdx.x & 63;
  int w = threadIdx.x >> 6;
  float* gt = gt_all[w];
  int wid = __builtin_amdgcn_readfirstlane(blockIdx.x * 4 + w);
  int c16 = l & 15, kg = l >> 4;

  // preload B fragments: b1 = We k 0..31, b2 = We k 32..47 (lanes kg>=2 zero)
  h8v b1[8], b2[8];
#pragma unroll
  for (int T = 0; T < 8; ++T) {
    h8v v1 = {0,0,0,0,0,0,0,0}, v2 = {0,0,0,0,0,0,0,0};
#pragma unroll
    for (int j = 0; j < 8; ++j)
      v1[j] = (_Float16)We[(kg * 8 + j) * 128 + T * 16 + c16];
    if (kg < 2) {
#pragma unroll
      for (int j = 0; j < 8; ++j) {
        int k = 32 + kg * 8 + j;
        v2[j] = (k < KE) ? (_Float16)We[k * 128 + T * 16 + c16] : (_Float16)0.f;
      }
    }
    b1[T] = v1; b2[T] = v2;
  }

  float sc0 = 0, sh0 = 0, sc1 = 0, sh1 = 0;
  if (APPLY) { sc0 = scsh[l]; sc1 = scsh[l + 64]; sh0 = scsh[128 + l]; sh1 = scsh[192 + l]; }
  float s0 = 0, q0 = 0, s1 = 0, q1 = 0;

  for (int n = wid; n < NA; n += CONV_WAVES) {
    // A fragments: row m = c16 (rows 12..15 zero via exec mask)
    const uint* ep = EF + (size_t)n * (MN * ROWDW);
    h8v a1 = {0,0,0,0,0,0,0,0}, a2 = {0,0,0,0,0,0,0,0};
    if (c16 < MN) {
      a1 = *(const h8v*)(ep + c16 * ROWDW + kg * 4);
      if (kg < 2) a2 = *(const h8v*)(ep + c16 * ROWDW + 16 + kg * 4);
    }
    f4v acc[8];
#pragma unroll
    for (int T = 0; T < 8; ++T) acc[T] = f4v{0.f, 0.f, 0.f, 0.f};
#pragma unroll
    for (int T = 0; T < 8; ++T)
      acc[T] = __builtin_amdgcn_mfma_f32_16x16x32_f16(a1, b1[T], acc[T], 0, 0, 0);
#pragma unroll
    for (int T = 0; T < 8; ++T)
      acc[T] = __builtin_amdgcn_mfma_f32_16x16x32_f16(a2, b2[T], acc[T], 0, 0, 0);

    // stage to LDS: row = kg*4+r, col = T*16+c16 (stride 132 -> 2-way max, free)
#pragma unroll
    for (int T = 0; T < 8; ++T)
#pragma unroll
      for (int r = 0; r < 4; ++r)
        gt[(kg * 4 + r) * 132 + T * 16 + c16] = acc[T][r];

    // epilogue in col-ownership layout: lane l owns cols {l, l+64}
    const int* ip = idx + n * MN;                      // n wave-uniform -> s_load
    H2U sp; sp.u = hWs[(size_t)n * 64 + l];
    float self0 = (float)sp.h[0], self1 = (float)sp.h[1];
    uint nbp[MN];
#pragma unroll
    for (int m = 0; m < MN; ++m) nbp[m] = hWn[(size_t)ip[m] * 64 + l];
    float accsum = 0.f;
#pragma unroll
    for (int m = 0; m < MN; ++m) {
      H2U nv; nv.u = nbp[m];
      float g0 = gt[m * 132 + l]      + self0 + (float)nv.h[0];
      float g1 = gt[m * 132 + 64 + l] + self1 + (float)nv.h[1];
      if (APPLY) {
        float f  = sigmoidf(g0 * sc0 + sh0);
        float cr = softplusf(g1 * sc1 + sh1);
        accsum += f * cr;
      } else {
        s0 += g0; q0 += g0 * g0;
        s1 += g1; q1 += g1 * g1;
      }
    }
    if (APPLY) {
      summed[(size_t)n * 64 + l] = accsum;
      s0 += accsum; q0 += accsum * accsum;             // BN2 stats
    }
  }
  if (APPLY) {
    atomicAdd(&stats[l], s0);
    atomicAdd(&stats[64 + l], q0);
  } else {
    atomicAdd(&stats[l], s0);
    atomicAdd(&stats[64 + l], s1);
    atomicAdd(&stats[128 + l], q0);
    atomicAdd(&stats[192 + l], q1);
  }
}

// ---- BN finalize ----
__global__ void k_fin1(const float* __restrict__ st, const float* __restrict__ g,
                       const float* __restrict__ b, float* __restrict__ scsh)
{
  int j = threadIdx.x;                 // 128
  float inv = 1.f / (float)(NA * MN);
  float mean = st[j] * inv;
  float var  = st[128 + j] * inv - mean * mean;
  float rstd = rsqrtf(var + EPSBN);
  float sc = g[j] * rstd;
  scsh[j] = sc;
  scsh[128 + j] = b[j] - mean * sc;
}
__global__ void k_fin2(const float* __restrict__ st, const float* __restrict__ g,
                       const float* __restrict__ b, float* __restrict__ scsh)
{
  int j = threadIdx.x;                 // 64
  float inv = 1.f / (float)NA;
  float mean = st[j] * inv;
  float var  = st[64 + j] * inv - mean * mean;
  float rstd = rsqrtf(var + EPSBN);
  float sc = g[j] * rstd;
  scsh[j] = sc;
  scsh[64 + j] = b[j] - mean * sc;
}

// ---- h = softplus(h + BN2(summed)) ----
__global__ __launch_bounds__(256) void k_bn2res(float* __restrict__ h,
                                                const float* __restrict__ summed,
                                                const float* __restrict__ scsh)
{
  int tot = NA * 64 / 4;
  const float4* s4 = (const float4*)summed;
  float4* h4 = (float4*)h;
  for (int i = blockIdx.x * blockDim.x + threadIdx.x; i < tot; i += gridDim.x * blockDim.x) {
    int c4 = i & 15;
    float4 sc = ((const float4*)scsh)[c4];
    float4 sh = ((const float4*)(scsh + 64))[c4];
    float4 hv = h4[i], sv = s4[i];
    hv.x = softplusf(hv.x + sv.x * sc.x + sh.x);
    hv.y = softplusf(hv.y + sv.y * sc.y + sh.y);
    hv.z = softplusf(hv.z + sv.z * sc.z + sh.z);
    hv.w = softplusf(hv.w + sv.w * sc.w + sh.w);
    h4[i] = hv;
  }
}

// ---- segment-sum pool (crystal_atom_idx sorted) ----
__global__ __launch_bounds__(256) void k_pool(const float* __restrict__ h,
                                              const int* __restrict__ cidx,
                                              float* __restrict__ csum,
                                              float* __restrict__ ccnt, int nw)
{
  int t = threadIdx.x & 63;
  int wid = waveid();
  int chunk = (NA + nw - 1) / nw;
  int n0 = wid * chunk;
  int n1 = min(n0 + chunk, NA);
  if (n0 >= NA) return;
  float acc = 0.f, cacc = 0.f;
  int cur = -1;
  for (int n = n0; n < n1; ++n) {
    int ci = cidx[n];
    if (ci != cur) {
      if (cur >= 0) {
        atomicAdd(&csum[(size_t)cur * 64 + t], acc);
        if (t == 0) atomicAdd(&ccnt[cur], cacc);
      }
      cur = ci; acc = 0.f; cacc = 0.f;
    }
    acc += h[(size_t)n * 64 + t];
    cacc += 1.f;
  }
  if (cur >= 0) {
    atomicAdd(&csum[(size_t)cur * 64 + t], acc);
    if (t == 0) atomicAdd(&ccnt[cur], cacc);
  }
}

// ---- head ----
__global__ __launch_bounds__(256) void k_head(const float* __restrict__ csum,
                                              const float* __restrict__ ccnt,
                                              const float* __restrict__ Wh,   // (64,128)
                                              const float* __restrict__ bh,
                                              const float* __restrict__ Wo,   // (128,1)
                                              const float* __restrict__ bo,
                                              float* __restrict__ out)
{
  __shared__ float Wl[64 * 128];
  for (int i = threadIdx.x; i < 64 * 128; i += 256) Wl[i] = Wh[i];
  __syncthreads();
  int t = threadIdx.x & 63;
  int ci = blockIdx.x * 4 + (threadIdx.x >> 6);
  if (ci >= N0C) return;
  float cnt = fmaxf(ccnt[ci], 1.f);
  float x = softplusf(csum[(size_t)ci * 64 + t] / cnt);
  float acc0 = 0.f, acc1 = 0.f;
#pragma unroll 4
  for (int c = 0; c < 64; ++c) {
    float xc = __shfl(x, c, 64);
    acc0 += xc * Wl[c * 128 + t];
    acc1 += xc * Wl[c * 128 + 64 + t];
  }
  float z0 = softplusf(acc0 + bh[t]);
  float z1 = softplusf(acc1 + bh[64 + t]);
  float part = z0 * Wo[t] + z1 * Wo[64 + t];
#pragma unroll
  for (int s = 32; s >= 1; s >>= 1) part += __shfl_xor(part, s, 64);
  if (t == 0) out[ci] = part + bo[0];
}

extern "C" void kernel_launch(void* const* d_in, const int* in_sizes, int n_in,
                              void* d_out, int out_size, void* d_ws, size_t ws_size,
                              hipStream_t stream)
{
  const float* af    = (const float*)d_in[0];
  const float* nbr   = (const float*)d_in[1];
  const int*   nidx  = (const int*)d_in[2];
  const int*   cidx  = (const int*)d_in[3];
  const float* embW  = (const float*)d_in[4];
  const float* embB  = (const float*)d_in[5];
  const float* fcW   = (const float*)d_in[6];
  // d_in[7] = fc_b: cancelled by BatchNorm mean subtraction
  const float* bn1g  = (const float*)d_in[8];
  const float* bn1b  = (const float*)d_in[9];
  const float* bn2g  = (const float*)d_in[10];
  const float* bn2b  = (const float*)d_in[11];
  const float* headW = (const float*)d_in[12];
  const float* headB = (const float*)d_in[13];
  const float* outW  = (const float*)d_in[14];
  const float* outB  = (const float*)d_in[15];
  float* out = (float*)d_out;

  float* ws = (float*)d_ws;
  size_t off = 0;
  float* h      = ws + off; off += (size_t)NA * 64;                 // 25.6 MB
  uint*  hWs    = (uint*)(ws + off); off += (size_t)NA * 64;        // 25.6 MB
  uint*  hWn    = (uint*)(ws + off); off += (size_t)NA * 64;        // 25.6 MB
  uint*  EF     = (uint*)(ws + off); off += (size_t)NA * MN * ROWDW; // 115.2 MB
  float* summed = ws + off; off += (size_t)NA * 64;                 // 25.6 MB
  float* zr     = ws + off;
  float* stats1 = zr;                       // 3*256
  float* stats2 = stats1 + 3 * 256;         // 3*128
  float* csum   = stats2 + 3 * 128;         // 2500*64
  float* ccnt   = csum + (size_t)N0C * 64;  // 2500
  size_t zcount = 3 * 256 + 3 * 128 + (size_t)N0C * 64 + N0C;
  float* scsh1  = ccnt + N0C;               // 3*256
  float* scsh2  = scsh1 + 3 * 256;          // 3*128

  hipMemsetAsync(zr, 0, zcount * sizeof(float), stream);

  k_cast_e<<<4096, 256, 0, stream>>>(nbr, EF);
  k_embed<<<512, 256, 0, stream>>>(af, embW, embB, h, 2048);

  for (int l = 0; l < 3; ++l) {
    const float* Wl = fcW + (size_t)l * 169 * 128;
    const float* We = Wl + 128 * 128;
    k_hw<<<512, 256, 0, stream>>>(h, Wl, hWs, hWn, 2048);
    k_conv<0><<<CONV_BLOCKS, 256, 0, stream>>>(EF, hWs, hWn, nidx, We, nullptr, nullptr,
                                               stats1 + l * 256);
    k_fin1<<<1, 128, 0, stream>>>(stats1 + l * 256, bn1g + l * 128, bn1b + l * 128,
                                  scsh1 + l * 256);
    k_conv<1><<<CONV_BLOCKS, 256, 0, stream>>>(EF, hWs, hWn, nidx, We, scsh1 + l * 256,
                                               summed, stats2 + l * 128);
    k_fin2<<<1, 64, 0, stream>>>(stats2 + l * 128, bn2g + l * 64, bn2b + l * 64,
                                 scsh2 + l * 128);
    k_bn2res<<<2048, 256, 0, stream>>>(h, summed, scsh2 + l * 128);
  }

  k_pool<<<512, 256, 0, stream>>>(h, cidx, csum, ccnt, 2048);
  k_head<<<625, 256, 0, stream>>>(csum, ccnt, headW, headB, outW, outB, out);
}